// Round 13
// baseline (743.178 us; speedup 1.0000x reference)
//
#include <hip/hip_runtime.h>
#include <hip/hip_fp16.h>
#include <hip/hip_cooperative_groups.h>

// GCN: 4 layers, N=50000, E=640000, d=128 (last 128->40).
// R13: dispatch-count attack (R12 accounting: ~100us of inter-dispatch gap
// across 14 dispatches). (1) ONE cooperative setup kernel (zero+deg+scan+
// nrm+fill+featH-conv+W-conv) with grid.sync between phases. (2) gemm3
// fused into layer-2 MFMA GEMM via padded LDS tile (h16 layer-2 copy never
// touches HBM). 14 dispatches -> 8. aggh (gather wall) unchanged = control.

namespace cg = cooperative_groups;

#define DIM 128
#define CHUNK 1024
#define HS_LD 136          // padded LDS row stride (halves): 272B = 17x16B

typedef __attribute__((ext_vector_type(8))) _Float16 f16x8;
typedef __attribute__((ext_vector_type(4))) float f32x4;

// ---------------- cooperative setup: all prep in one launch ----------------
__global__ __launch_bounds__(256) void setup_kernel(
        const int* __restrict__ src, const int* __restrict__ dst,
        const float* __restrict__ features,
        const float* __restrict__ W0, const float* __restrict__ W1,
        const float* __restrict__ W2, const float* __restrict__ W3,
        int* __restrict__ deg, int* __restrict__ cur, float* __restrict__ nrm,
        int* __restrict__ off, int* __restrict__ bsum, int* __restrict__ csr,
        __half* __restrict__ featH, __half* __restrict__ Wt,
        int N, int E, int G) {
    cg::grid_group grid = cg::this_grid();
    __shared__ int ws[4];
    __shared__ int wsum[4];
    int t = threadIdx.x;
    int gtid = blockIdx.x * 256 + t;
    int gsz = gridDim.x * 256;

    // phase 0: zero deg+cur; build fp16 transposed weights Wt
    for (int i = gtid; i < N; i += gsz) { deg[i] = 0; cur[i] = 0; }
    const int WTOT = 3 * 128 * 128 + 48 * 128;
    for (int i = gtid; i < WTOT; i += gsz) {
        if (i < 3 * 128 * 128) {
            int l = i >> 14, c = (i >> 7) & 127, k = i & 127;
            const float* W = (l == 0) ? W0 : ((l == 1) ? W1 : W2);
            Wt[i] = __float2half(W[k * 128 + c]);
        } else {
            int j = i - 3 * 128 * 128, c = j >> 7, k = j & 127;
            Wt[i] = __float2half((c < 40) ? W3[k * 40 + c] : 0.f);
        }
    }
    grid.sync();

    // phase 1: degree histogram
    for (int i = gtid; i < E; i += gsz) atomicAdd(&deg[dst[i]], 1);
    grid.sync();

    // phase 2: nrm + per-chunk sums (block b < G owns chunk b)
    if (blockIdx.x < (unsigned)G) {
        int b = blockIdx.x;
        int base = b * CHUNK + t * 4;
        int s = 0;
        if (base + 3 < N) {
            int4 d = *(const int4*)&deg[base];
            s = d.x + d.y + d.z + d.w;
            float4 r;
            r.x = rsqrtf(fmaxf((float)d.x, 1.f));
            r.y = rsqrtf(fmaxf((float)d.y, 1.f));
            r.z = rsqrtf(fmaxf((float)d.z, 1.f));
            r.w = rsqrtf(fmaxf((float)d.w, 1.f));
            *(float4*)&nrm[base] = r;
        } else {
            for (int j2 = 0; j2 < 4; ++j2) {
                int idx = base + j2;
                if (idx < N) {
                    int d = deg[idx];
                    s += d;
                    nrm[idx] = rsqrtf(fmaxf((float)d, 1.f));
                }
            }
        }
        for (int o = 32; o; o >>= 1) s += __shfl_down(s, o, 64);
        if ((t & 63) == 0) ws[t >> 6] = s;
        __syncthreads();
        if (t == 0) bsum[b] = ws[0] + ws[1] + ws[2] + ws[3];
    }
    grid.sync();

    // phase 3: exclusive scan of bsum[G] (block 0, wave 0; G <= 64)
    if (blockIdx.x == 0 && t < 64) {
        int orig = (t < G) ? bsum[t] : 0;
        int v = orig;
        for (int o = 1; o < 64; o <<= 1) {
            int u = __shfl_up(v, o, 64);
            if (t >= o) v += u;
        }
        if (t < G) bsum[t] = v - orig;
        if (t == G - 1) off[N] = v;
    }
    grid.sync();

    // phase 4: per-chunk offsets (blocks < G) + featH = features*nrm (all)
    if (blockIdx.x < (unsigned)G) {
        int b = blockIdx.x;
        int base = b * CHUNK + t * 4;
        int d0 = 0, d1 = 0, d2 = 0, d3 = 0;
        if (base + 3 < N) {
            int4 d = *(const int4*)&deg[base];
            d0 = d.x; d1 = d.y; d2 = d.z; d3 = d.w;
        } else {
            if (base     < N) d0 = deg[base];
            if (base + 1 < N) d1 = deg[base + 1];
            if (base + 2 < N) d2 = deg[base + 2];
        }
        int tot = d0 + d1 + d2 + d3;
        int v = tot;
        for (int o = 1; o < 64; o <<= 1) {
            int u = __shfl_up(v, o, 64);
            if ((t & 63) >= o) v += u;
        }
        if ((t & 63) == 63) wsum[t >> 6] = v;
        __syncthreads();
        int wbase = 0;
        for (int w = 0; w < (t >> 6); ++w) wbase += wsum[w];
        int p = bsum[b] + wbase + (v - tot);
        if (base + 3 < N) {
            *(int4*)&off[base] = make_int4(p, p + d0, p + d0 + d1, p + d0 + d1 + d2);
        } else {
            if (base     < N) off[base]     = p;
            if (base + 1 < N) off[base + 1] = p + d0;
            if (base + 2 < N) off[base + 2] = p + d0 + d1;
        }
    }
    for (int i = gtid; i < N * 32; i += gsz) {
        int r = i >> 5, c4 = i & 31;
        float s = nrm[r];
        float4 v = ((const float4*)features)[i];
        __half2 lo = __float22half2_rn(make_float2(v.x * s, v.y * s));
        __half2 hi = __float22half2_rn(make_float2(v.z * s, v.w * s));
        uint2 u;
        u.x = *(unsigned int*)&lo;
        u.y = *(unsigned int*)&hi;
        *(uint2*)&featH[(size_t)r * DIM + c4 * 4] = u;
    }
    grid.sync();

    // phase 5: CSR fill
    for (int i = gtid; i < E; i += gsz) {
        int d = dst[i];
        int p2 = atomicAdd(&cur[d], 1);
        csr[off[d] + p2] = src[i];
    }
}

// ------------- fp16 gather (unchanged R11/R12 body — the control) ----------
__global__ __launch_bounds__(256) void aggh_kernel(
        const __half* __restrict__ hin, const float* __restrict__ nrm,
        const int* __restrict__ off, const int* __restrict__ csr,
        __half* __restrict__ out, int N) {
    int t = threadIdx.x;
    int lane = t & 63;
    int node = blockIdx.x * 4 + (t >> 6);
    if (node >= N) return;
    int pos = lane & 15, sg = lane >> 4;
    int c = pos * 8;
    int b = off[node], e = off[node + 1];
    float a[8] = {0,0,0,0,0,0,0,0};
    float bb[8] = {0,0,0,0,0,0,0,0};
    int j = b + sg;
    for (; j + 4 < e; j += 8) {
        int s0 = csr[j], s1 = csr[j + 4];
        uint4 u0 = *(const uint4*)&hin[(size_t)s0 * DIM + c];
        uint4 u1 = *(const uint4*)&hin[(size_t)s1 * DIM + c];
        float2 f;
        f = __half22float2(*(__half2*)&u0.x); a[0]+=f.x; a[1]+=f.y;
        f = __half22float2(*(__half2*)&u0.y); a[2]+=f.x; a[3]+=f.y;
        f = __half22float2(*(__half2*)&u0.z); a[4]+=f.x; a[5]+=f.y;
        f = __half22float2(*(__half2*)&u0.w); a[6]+=f.x; a[7]+=f.y;
        f = __half22float2(*(__half2*)&u1.x); bb[0]+=f.x; bb[1]+=f.y;
        f = __half22float2(*(__half2*)&u1.y); bb[2]+=f.x; bb[3]+=f.y;
        f = __half22float2(*(__half2*)&u1.z); bb[4]+=f.x; bb[5]+=f.y;
        f = __half22float2(*(__half2*)&u1.w); bb[6]+=f.x; bb[7]+=f.y;
    }
    for (; j < e; j += 4) {
        uint4 u = *(const uint4*)&hin[(size_t)csr[j] * DIM + c];
        float2 f;
        f = __half22float2(*(__half2*)&u.x); a[0]+=f.x; a[1]+=f.y;
        f = __half22float2(*(__half2*)&u.y); a[2]+=f.x; a[3]+=f.y;
        f = __half22float2(*(__half2*)&u.z); a[4]+=f.x; a[5]+=f.y;
        f = __half22float2(*(__half2*)&u.w); a[6]+=f.x; a[7]+=f.y;
    }
#pragma unroll
    for (int k = 0; k < 8; ++k) a[k] += bb[k];
#pragma unroll
    for (int k = 0; k < 8; ++k) {
        a[k] += __shfl_xor(a[k], 16, 64);
        a[k] += __shfl_xor(a[k], 32, 64);
    }
    if (sg == 0) {
        float s = nrm[node];
        __half2 h0 = __float22half2_rn(make_float2(a[0]*s, a[1]*s));
        __half2 h1 = __float22half2_rn(make_float2(a[2]*s, a[3]*s));
        __half2 h2 = __float22half2_rn(make_float2(a[4]*s, a[5]*s));
        __half2 h3 = __float22half2_rn(make_float2(a[6]*s, a[7]*s));
        uint4 u;
        u.x = *(unsigned int*)&h0; u.y = *(unsigned int*)&h1;
        u.z = *(unsigned int*)&h2; u.w = *(unsigned int*)&h3;
        *(uint4*)&out[(size_t)node * DIM + c] = u;
    }
}

// ---------------- MFMA GEMM (layers 0,1) — unchanged R12 -------------------
__global__ __launch_bounds__(256) void gemmM_kernel(
        const __half* __restrict__ Ah, const __half* __restrict__ Wt,
        const float* __restrict__ nrm, __half* __restrict__ outh, int n) {
    int t = threadIdx.x;
    int lane = t & 63, wv = t >> 6;
    int row0 = blockIdx.x * 64 + wv * 16;
    int arow = row0 + (lane & 15);
    int ar = (arow < n) ? arow : (n - 1);
    int kg = lane >> 4;

    const __half* Abase = Ah + (size_t)ar * DIM + kg * 8;
    f16x8 a[4];
#pragma unroll
    for (int k0 = 0; k0 < 4; ++k0)
        a[k0] = *(const f16x8*)(Abase + k0 * 32);

    f32x4 acc[8];
#pragma unroll
    for (int ct = 0; ct < 8; ++ct) {
        acc[ct] = (f32x4){0.f, 0.f, 0.f, 0.f};
        const __half* Bbase = Wt + (size_t)(ct * 16 + (lane & 15)) * DIM + kg * 8;
#pragma unroll
        for (int k0 = 0; k0 < 4; ++k0) {
            f16x8 b = *(const f16x8*)(Bbase + k0 * 32);
            acc[ct] = __builtin_amdgcn_mfma_f32_16x16x32_f16(a[k0], b, acc[ct], 0, 0, 0);
        }
    }

    int col = lane & 15;
    int rbase = row0 + (lane >> 4) * 4;
#pragma unroll
    for (int r = 0; r < 4; ++r) {
        int row = rbase + r;
        if (row >= n) continue;
        float s = nrm[row];
#pragma unroll
        for (int ct = 0; ct < 8; ++ct) {
            float v = fmaxf(acc[ct][r], 0.f) * s;
            outh[(size_t)row * DIM + ct * 16 + col] = __float2half(v);
        }
    }
}

// ------- Fused layer-2 GEMM + layer-3 GEMM (h16 tile stays in LDS) ---------
__global__ __launch_bounds__(256) void gemmM2_kernel(
        const __half* __restrict__ Ah, const __half* __restrict__ Wt2,
        const __half* __restrict__ Wt3, const float* __restrict__ nrm,
        __half* __restrict__ g3h, int n) {
    __shared__ __half Hs[64 * HS_LD];      // padded: no 16-way b128 conflicts
    int t = threadIdx.x;
    int lane = t & 63, wv = t >> 6;
    int row0 = blockIdx.x * 64 + wv * 16;
    int arow = row0 + (lane & 15);
    int ar = (arow < n) ? arow : (n - 1);
    int kg = lane >> 4;

    const __half* Abase = Ah + (size_t)ar * DIM + kg * 8;
    f16x8 a[4];
#pragma unroll
    for (int k0 = 0; k0 < 4; ++k0)
        a[k0] = *(const f16x8*)(Abase + k0 * 32);

    f32x4 acc[8];
#pragma unroll
    for (int ct = 0; ct < 8; ++ct) {
        acc[ct] = (f32x4){0.f, 0.f, 0.f, 0.f};
        const __half* Bbase = Wt2 + (size_t)(ct * 16 + (lane & 15)) * DIM + kg * 8;
#pragma unroll
        for (int k0 = 0; k0 < 4; ++k0) {
            f16x8 b = *(const f16x8*)(Bbase + k0 * 32);
            acc[ct] = __builtin_amdgcn_mfma_f32_16x16x32_f16(a[k0], b, acc[ct], 0, 0, 0);
        }
    }

    // epilogue -> LDS tile (relu + nrm); rows >= n zeroed
    int col = lane & 15;
    int lr0 = wv * 16 + (lane >> 4) * 4;
#pragma unroll
    for (int r = 0; r < 4; ++r) {
        int lrow = lr0 + r;
        int grow = blockIdx.x * 64 + lrow;
        float s = (grow < n) ? nrm[grow] : 0.f;
#pragma unroll
        for (int ct = 0; ct < 8; ++ct) {
            float v = fmaxf(acc[ct][r], 0.f) * s;
            Hs[lrow * HS_LD + ct * 16 + col] = __float2half(v);
        }
    }
    __syncthreads();

    // part 2: [64x48] = Hs @ Wt3 (3 col-tiles), store [n][40] fp16
    int lrowA = wv * 16 + (lane & 15);
    const __half* Hbase = &Hs[lrowA * HS_LD + kg * 8];
    f16x8 a2[4];
#pragma unroll
    for (int k0 = 0; k0 < 4; ++k0)
        a2[k0] = *(const f16x8*)(Hbase + k0 * 32);

    f32x4 acc2[3];
#pragma unroll
    for (int ct = 0; ct < 3; ++ct) {
        acc2[ct] = (f32x4){0.f, 0.f, 0.f, 0.f};
        const __half* Bbase = Wt3 + (size_t)(ct * 16 + (lane & 15)) * DIM + kg * 8;
#pragma unroll
        for (int k0 = 0; k0 < 4; ++k0) {
            f16x8 b = *(const f16x8*)(Bbase + k0 * 32);
            acc2[ct] = __builtin_amdgcn_mfma_f32_16x16x32_f16(a2[k0], b, acc2[ct], 0, 0, 0);
        }
    }

    int rbase = row0 + (lane >> 4) * 4;
#pragma unroll
    for (int r = 0; r < 4; ++r) {
        int row = rbase + r;
        if (row >= n) continue;
#pragma unroll
        for (int ct = 0; ct < 3; ++ct) {
            int cc = ct * 16 + col;
            if (cc < 40)
                g3h[(size_t)row * 40 + cc] = __float2half(acc2[ct][r]);
        }
    }
}

// ---------- final agg over fp16 [N][40] rows -> fp32 d_out (unchanged) -----
__global__ __launch_bounds__(256) void agg40_kernel(
        const __half* __restrict__ hin, const float* __restrict__ nrm,
        const int* __restrict__ off, const int* __restrict__ csr,
        float* __restrict__ out, int N) {
    int t = threadIdx.x;
    int lane = t & 63, wv = t >> 6;
    int g = lane >> 4, pos = lane & 15;
    int node = blockIdx.x * 16 + wv * 4 + g;
    if (node >= N || pos >= 10) return;
    int b = off[node], e = off[node + 1];
    float4 a0 = make_float4(0,0,0,0), a1 = a0, a2 = a0, a3 = a0;
    int j = b;
    for (; j + 3 < e; j += 4) {
        int s0 = csr[j], s1 = csr[j+1], s2 = csr[j+2], s3 = csr[j+3];
        uint2 u0 = *(const uint2*)&hin[(size_t)s0 * 40 + pos * 4];
        uint2 u1 = *(const uint2*)&hin[(size_t)s1 * 40 + pos * 4];
        uint2 u2 = *(const uint2*)&hin[(size_t)s2 * 40 + pos * 4];
        uint2 u3 = *(const uint2*)&hin[(size_t)s3 * 40 + pos * 4];
        float2 f;
        f = __half22float2(*(__half2*)&u0.x); a0.x+=f.x; a0.y+=f.y;
        f = __half22float2(*(__half2*)&u0.y); a0.z+=f.x; a0.w+=f.y;
        f = __half22float2(*(__half2*)&u1.x); a1.x+=f.x; a1.y+=f.y;
        f = __half22float2(*(__half2*)&u1.y); a1.z+=f.x; a1.w+=f.y;
        f = __half22float2(*(__half2*)&u2.x); a2.x+=f.x; a2.y+=f.y;
        f = __half22float2(*(__half2*)&u2.y); a2.z+=f.x; a2.w+=f.y;
        f = __half22float2(*(__half2*)&u3.x); a3.x+=f.x; a3.y+=f.y;
        f = __half22float2(*(__half2*)&u3.y); a3.z+=f.x; a3.w+=f.y;
    }
    for (; j < e; ++j) {
        uint2 u = *(const uint2*)&hin[(size_t)csr[j] * 40 + pos * 4];
        float2 f;
        f = __half22float2(*(__half2*)&u.x); a0.x+=f.x; a0.y+=f.y;
        f = __half22float2(*(__half2*)&u.y); a0.z+=f.x; a0.w+=f.y;
    }
    float s = nrm[node];
    float4 r;
    r.x = ((a0.x+a1.x) + (a2.x+a3.x)) * s;
    r.y = ((a0.y+a1.y) + (a2.y+a3.y)) * s;
    r.z = ((a0.z+a1.z) + (a2.z+a3.z)) * s;
    r.w = ((a0.w+a1.w) + (a2.w+a3.w)) * s;
    *(float4*)&out[(size_t)node * 40 + pos * 4] = r;
}

extern "C" void kernel_launch(void* const* d_in, const int* in_sizes, int n_in,
                              void* d_out, int out_size, void* d_ws, size_t ws_size,
                              hipStream_t stream) {
    const float* features = (const float*)d_in[0];
    const int*   edges    = (const int*)d_in[1];
    const float* W0       = (const float*)d_in[2];
    const float* W1       = (const float*)d_in[3];
    const float* W2       = (const float*)d_in[4];
    const float* W3       = (const float*)d_in[5];

    const int N = in_sizes[0] / DIM;       // 50000
    const int E = in_sizes[1] / 2;         // 640000
    const int* src = edges;
    const int* dst = edges + E;

    char* p = (char*)d_ws;
    __half* featH = (__half*)p; p += (size_t)N * DIM * 2;   // prescaled features
    __half* agg16 = (__half*)p; p += (size_t)N * DIM * 2;   // agg out (pre-GEMM)
    __half* h16   = (__half*)p; p += (size_t)N * DIM * 2;   // gemm out (h1/h2)
    __half* g3h   = (__half*)p; p += (size_t)N * 64 * 2;    // layer-3 out [N][40]
    __half* Wt    = (__half*)p; p += (size_t)(3 * 128 * 128 + 48 * 128) * 2;
    float*  nrm   = (float*)p;  p += (size_t)N * 4;
    int*    deg   = (int*)p;    p += (size_t)N * 4;
    int*    cur   = (int*)p;    p += (size_t)N * 4;
    int*    off   = (int*)p;    p += (size_t)(N + 1) * 4;
    int*    bsum  = (int*)p;    p += 64 * 4;
    int*    csr   = (int*)p;    p += (size_t)E * 4;
    (void)ws_size; (void)n_in; (void)out_size;

    int Gv = (N + CHUNK - 1) / CHUNK;      // 49
    {
        // locals so &x is valid for the params array
        const int* a0 = src; const int* a1 = dst;
        const float* a2 = features;
        const float* a3 = W0; const float* a4 = W1;
        const float* a5 = W2; const float* a6 = W3;
        int* a7 = deg; int* a8 = cur; float* a9 = nrm;
        int* a10 = off; int* a11 = bsum; int* a12 = csr;
        __half* a13 = featH; __half* a14 = Wt;
        int a15 = N, a16 = E, a17 = Gv;
        void* args[] = {&a0, &a1, &a2, &a3, &a4, &a5, &a6, &a7, &a8, &a9,
                        &a10, &a11, &a12, &a13, &a14, &a15, &a16, &a17};
        hipLaunchCooperativeKernel((const void*)setup_kernel,
                                   dim3(1024), dim3(256), args, 0, stream);
    }

    int gb = (N + 63) / 64;
    int ab = (N + 3) / 4;
    aggh_kernel<<<ab, 256, 0, stream>>>(featH, nrm, off, csr, agg16, N);
    gemmM_kernel<<<gb, 256, 0, stream>>>(agg16, Wt, nrm, h16, N);

    aggh_kernel<<<ab, 256, 0, stream>>>(h16, nrm, off, csr, agg16, N);
    gemmM_kernel<<<gb, 256, 0, stream>>>(agg16, Wt + 128 * 128, nrm, h16, N);

    aggh_kernel<<<ab, 256, 0, stream>>>(h16, nrm, off, csr, agg16, N);
    gemmM2_kernel<<<gb, 256, 0, stream>>>(agg16, Wt + 2 * 128 * 128,
                                          Wt + 3 * 128 * 128, nrm, g3h, N);

    agg40_kernel<<<(N + 15) / 16, 256, 0, stream>>>(g3h, nrm, off, csr,
                                                    (float*)d_out, N);
}

// Round 14
// 252.253 us; speedup vs baseline: 2.9462x; 2.9462x over previous
//
#include <hip/hip_runtime.h>
#include <hip/hip_fp16.h>

// GCN: 4 layers, N=50000, E=640000, d=128 (last 128->40).
// R14: R12 structure restored (R13's cooperative grid.sync = ~100us/sync on
// 8-XCD gfx950 — dead). Kept from R13: gemmM2 (layer-2 GEMM + layer-3 GEMM
// fused via LDS tile). New: convW merged into conv (one prep kernel).
// 12 dispatches. aggh (gather wall ~29-30us) is the control.

#define DIM 128
#define CHUNK 1024
#define HS_LD 136          // padded LDS row stride (halves)

typedef __attribute__((ext_vector_type(8))) _Float16 f16x8;
typedef __attribute__((ext_vector_type(4))) float f32x4;

__global__ void deg_kernel(const int* __restrict__ dst, int* __restrict__ deg, int E) {
    int i = blockIdx.x * blockDim.x + threadIdx.x;
    if (i < E) atomicAdd(&deg[dst[i]], 1);
}

// Phase A: per-chunk sums of deg; also computes nrm = rsqrt(max(deg,1)).
__global__ __launch_bounds__(256) void scanA_kernel(
        const int* __restrict__ deg, float* __restrict__ nrm,
        int* __restrict__ bsum, int n) {
    int b = blockIdx.x, t = threadIdx.x;
    int base = b * CHUNK + t * 4;
    int s = 0;
    if (base + 3 < n) {
        int4 d = *(const int4*)&deg[base];
        s = d.x + d.y + d.z + d.w;
        float4 r;
        r.x = rsqrtf(fmaxf((float)d.x, 1.0f));
        r.y = rsqrtf(fmaxf((float)d.y, 1.0f));
        r.z = rsqrtf(fmaxf((float)d.z, 1.0f));
        r.w = rsqrtf(fmaxf((float)d.w, 1.0f));
        *(float4*)&nrm[base] = r;
    } else {
        for (int j = 0; j < 4; ++j) {
            int idx = base + j;
            if (idx < n) {
                int d = deg[idx];
                s += d;
                nrm[idx] = rsqrtf(fmaxf((float)d, 1.0f));
            }
        }
    }
    for (int o = 32; o; o >>= 1) s += __shfl_down(s, o, 64);
    __shared__ int ws[4];
    if ((t & 63) == 0) ws[t >> 6] = s;
    __syncthreads();
    if (t == 0) bsum[b] = ws[0] + ws[1] + ws[2] + ws[3];
}

// Merged B+C: wave 0 scans bsum[G] in registers; zero cur; per-chunk offsets.
__global__ __launch_bounds__(256) void scanBC_kernel(
        const int* __restrict__ deg, const int* __restrict__ bsum,
        int* __restrict__ off, int* __restrict__ cur, int n, int G) {
    __shared__ int pbs;
    __shared__ int wsum[4];
    int b = blockIdx.x, t = threadIdx.x;
    if (t < 64) {
        int orig = (t < G) ? bsum[t] : 0;
        int v = orig;
        for (int o = 1; o < 64; o <<= 1) {
            int u = __shfl_up(v, o, 64);
            if (t >= o) v += u;
        }
        if (b == 0 && t == G - 1) off[n] = v;   // grand total
        if (t == b) pbs = v - orig;             // exclusive prefix of chunk b
    }
    int base = b * CHUNK + t * 4;
    if (base + 3 < n) *(int4*)&cur[base] = make_int4(0, 0, 0, 0);
    else for (int j = 0; j < 4; ++j) if (base + j < n) cur[base + j] = 0;

    int d0 = 0, d1 = 0, d2 = 0, d3 = 0;
    if (base + 3 < n) {
        int4 d = *(const int4*)&deg[base];
        d0 = d.x; d1 = d.y; d2 = d.z; d3 = d.w;
    } else {
        if (base     < n) d0 = deg[base];
        if (base + 1 < n) d1 = deg[base + 1];
        if (base + 2 < n) d2 = deg[base + 2];
    }
    int tot = d0 + d1 + d2 + d3;
    int v = tot;
    for (int o = 1; o < 64; o <<= 1) {
        int u = __shfl_up(v, o, 64);
        if ((t & 63) >= o) v += u;
    }
    if ((t & 63) == 63) wsum[t >> 6] = v;
    __syncthreads();
    int wbase = 0;
    for (int w = 0; w < (t >> 6); ++w) wbase += wsum[w];
    int p = pbs + wbase + (v - tot);
    if (base + 3 < n) {
        int4 o4 = make_int4(p, p + d0, p + d0 + d1, p + d0 + d1 + d2);
        *(int4*)&off[base] = o4;
    } else {
        if (base     < n) off[base]     = p;
        if (base + 1 < n) off[base + 1] = p + d0;
        if (base + 2 < n) off[base + 2] = p + d0 + d1;
    }
}

__global__ void fill_kernel(const int* __restrict__ src, const int* __restrict__ dst,
                            const int* __restrict__ off, int* __restrict__ cur,
                            int* __restrict__ csr, int E) {
    int i = blockIdx.x * blockDim.x + threadIdx.x;
    if (i < E) {
        int d = dst[i];
        int p = atomicAdd(&cur[d], 1);
        csr[off[d] + p] = src[i];
    }
}

// Merged prep: featH = features*nrm (fp16) AND Wt (fp16 transposed weights).
// i < N*32: conv. i >= N*32: weight transpose (55296 items).
__global__ void prep_kernel(const float* __restrict__ f, const float* __restrict__ nrm,
                            const float* __restrict__ W0, const float* __restrict__ W1,
                            const float* __restrict__ W2, const float* __restrict__ W3,
                            __half* __restrict__ featH, __half* __restrict__ Wt,
                            int n4) {
    int i = blockIdx.x * blockDim.x + threadIdx.x;
    if (i < n4) {
        int r = i >> 5, c4 = i & 31;
        float s = nrm[r];
        float4 v = ((const float4*)f)[i];
        __half2 lo = __float22half2_rn(make_float2(v.x * s, v.y * s));
        __half2 hi = __float22half2_rn(make_float2(v.z * s, v.w * s));
        uint2 u;
        u.x = *(unsigned int*)&lo;
        u.y = *(unsigned int*)&hi;
        *(uint2*)&featH[(size_t)r * DIM + c4 * 4] = u;
    } else {
        int w = i - n4;
        if (w < 3 * 128 * 128) {
            int l = w >> 14, c = (w >> 7) & 127, k = w & 127;
            const float* W = (l == 0) ? W0 : ((l == 1) ? W1 : W2);
            Wt[w] = __float2half(W[k * 128 + c]);
        } else if (w < 3 * 128 * 128 + 48 * 128) {
            int j = w - 3 * 128 * 128;
            int c = j >> 7, k = j & 127;
            Wt[w] = __float2half((c < 40) ? W3[k * 40 + c] : 0.f);
        }
    }
}

// fp16 gather (the control — at the gather wall): quarter-wave per edge.
__global__ __launch_bounds__(256) void aggh_kernel(
        const __half* __restrict__ hin, const float* __restrict__ nrm,
        const int* __restrict__ off, const int* __restrict__ csr,
        __half* __restrict__ out, int N) {
    int t = threadIdx.x;
    int lane = t & 63;
    int node = blockIdx.x * 4 + (t >> 6);
    if (node >= N) return;
    int pos = lane & 15, sg = lane >> 4;
    int c = pos * 8;
    int b = off[node], e = off[node + 1];
    float a[8] = {0,0,0,0,0,0,0,0};
    float bb[8] = {0,0,0,0,0,0,0,0};
    int j = b + sg;
    for (; j + 4 < e; j += 8) {
        int s0 = csr[j], s1 = csr[j + 4];
        uint4 u0 = *(const uint4*)&hin[(size_t)s0 * DIM + c];
        uint4 u1 = *(const uint4*)&hin[(size_t)s1 * DIM + c];
        float2 f;
        f = __half22float2(*(__half2*)&u0.x); a[0]+=f.x; a[1]+=f.y;
        f = __half22float2(*(__half2*)&u0.y); a[2]+=f.x; a[3]+=f.y;
        f = __half22float2(*(__half2*)&u0.z); a[4]+=f.x; a[5]+=f.y;
        f = __half22float2(*(__half2*)&u0.w); a[6]+=f.x; a[7]+=f.y;
        f = __half22float2(*(__half2*)&u1.x); bb[0]+=f.x; bb[1]+=f.y;
        f = __half22float2(*(__half2*)&u1.y); bb[2]+=f.x; bb[3]+=f.y;
        f = __half22float2(*(__half2*)&u1.z); bb[4]+=f.x; bb[5]+=f.y;
        f = __half22float2(*(__half2*)&u1.w); bb[6]+=f.x; bb[7]+=f.y;
    }
    for (; j < e; j += 4) {
        uint4 u = *(const uint4*)&hin[(size_t)csr[j] * DIM + c];
        float2 f;
        f = __half22float2(*(__half2*)&u.x); a[0]+=f.x; a[1]+=f.y;
        f = __half22float2(*(__half2*)&u.y); a[2]+=f.x; a[3]+=f.y;
        f = __half22float2(*(__half2*)&u.z); a[4]+=f.x; a[5]+=f.y;
        f = __half22float2(*(__half2*)&u.w); a[6]+=f.x; a[7]+=f.y;
    }
#pragma unroll
    for (int k = 0; k < 8; ++k) a[k] += bb[k];
#pragma unroll
    for (int k = 0; k < 8; ++k) {
        a[k] += __shfl_xor(a[k], 16, 64);
        a[k] += __shfl_xor(a[k], 32, 64);
    }
    if (sg == 0) {
        float s = nrm[node];
        __half2 h0 = __float22half2_rn(make_float2(a[0]*s, a[1]*s));
        __half2 h1 = __float22half2_rn(make_float2(a[2]*s, a[3]*s));
        __half2 h2 = __float22half2_rn(make_float2(a[4]*s, a[5]*s));
        __half2 h3 = __float22half2_rn(make_float2(a[6]*s, a[7]*s));
        uint4 u;
        u.x = *(unsigned int*)&h0; u.y = *(unsigned int*)&h1;
        u.z = *(unsigned int*)&h2; u.w = *(unsigned int*)&h3;
        *(uint4*)&out[(size_t)node * DIM + c] = u;
    }
}

// MFMA GEMM (layers 0,1): C[64x128] = A @ Wt, relu+nrm, fp16 out.
__global__ __launch_bounds__(256) void gemmM_kernel(
        const __half* __restrict__ Ah, const __half* __restrict__ Wt,
        const float* __restrict__ nrm, __half* __restrict__ outh, int n) {
    int t = threadIdx.x;
    int lane = t & 63, wv = t >> 6;
    int row0 = blockIdx.x * 64 + wv * 16;
    int arow = row0 + (lane & 15);
    int ar = (arow < n) ? arow : (n - 1);
    int kg = lane >> 4;

    const __half* Abase = Ah + (size_t)ar * DIM + kg * 8;
    f16x8 a[4];
#pragma unroll
    for (int k0 = 0; k0 < 4; ++k0)
        a[k0] = *(const f16x8*)(Abase + k0 * 32);

    f32x4 acc[8];
#pragma unroll
    for (int ct = 0; ct < 8; ++ct) {
        acc[ct] = (f32x4){0.f, 0.f, 0.f, 0.f};
        const __half* Bbase = Wt + (size_t)(ct * 16 + (lane & 15)) * DIM + kg * 8;
#pragma unroll
        for (int k0 = 0; k0 < 4; ++k0) {
            f16x8 b = *(const f16x8*)(Bbase + k0 * 32);
            acc[ct] = __builtin_amdgcn_mfma_f32_16x16x32_f16(a[k0], b, acc[ct], 0, 0, 0);
        }
    }

    int col = lane & 15;
    int rbase = row0 + (lane >> 4) * 4;
#pragma unroll
    for (int r = 0; r < 4; ++r) {
        int row = rbase + r;
        if (row >= n) continue;
        float s = nrm[row];
#pragma unroll
        for (int ct = 0; ct < 8; ++ct) {
            float v = fmaxf(acc[ct][r], 0.f) * s;
            outh[(size_t)row * DIM + ct * 16 + col] = __float2half(v);
        }
    }
}

// Fused layer-2 GEMM + layer-3 GEMM (h2 tile stays in LDS; kept from R13).
__global__ __launch_bounds__(256) void gemmM2_kernel(
        const __half* __restrict__ Ah, const __half* __restrict__ Wt2,
        const __half* __restrict__ Wt3, const float* __restrict__ nrm,
        __half* __restrict__ g3h, int n) {
    __shared__ __half Hs[64 * HS_LD];
    int t = threadIdx.x;
    int lane = t & 63, wv = t >> 6;
    int row0 = blockIdx.x * 64 + wv * 16;
    int arow = row0 + (lane & 15);
    int ar = (arow < n) ? arow : (n - 1);
    int kg = lane >> 4;

    const __half* Abase = Ah + (size_t)ar * DIM + kg * 8;
    f16x8 a[4];
#pragma unroll
    for (int k0 = 0; k0 < 4; ++k0)
        a[k0] = *(const f16x8*)(Abase + k0 * 32);

    f32x4 acc[8];
#pragma unroll
    for (int ct = 0; ct < 8; ++ct) {
        acc[ct] = (f32x4){0.f, 0.f, 0.f, 0.f};
        const __half* Bbase = Wt2 + (size_t)(ct * 16 + (lane & 15)) * DIM + kg * 8;
#pragma unroll
        for (int k0 = 0; k0 < 4; ++k0) {
            f16x8 b = *(const f16x8*)(Bbase + k0 * 32);
            acc[ct] = __builtin_amdgcn_mfma_f32_16x16x32_f16(a[k0], b, acc[ct], 0, 0, 0);
        }
    }

    // epilogue -> LDS tile (relu + nrm); rows >= n zeroed
    int col = lane & 15;
    int lr0 = wv * 16 + (lane >> 4) * 4;
#pragma unroll
    for (int r = 0; r < 4; ++r) {
        int lrow = lr0 + r;
        int grow = blockIdx.x * 64 + lrow;
        float s = (grow < n) ? nrm[grow] : 0.f;
#pragma unroll
        for (int ct = 0; ct < 8; ++ct) {
            float v = fmaxf(acc[ct][r], 0.f) * s;
            Hs[lrow * HS_LD + ct * 16 + col] = __float2half(v);
        }
    }
    __syncthreads();

    // part 2: [64x48] = Hs @ Wt3 (3 col-tiles), store [n][40] fp16
    int lrowA = wv * 16 + (lane & 15);
    const __half* Hbase = &Hs[lrowA * HS_LD + kg * 8];
    f16x8 a2[4];
#pragma unroll
    for (int k0 = 0; k0 < 4; ++k0)
        a2[k0] = *(const f16x8*)(Hbase + k0 * 32);

    f32x4 acc2[3];
#pragma unroll
    for (int ct = 0; ct < 3; ++ct) {
        acc2[ct] = (f32x4){0.f, 0.f, 0.f, 0.f};
        const __half* Bbase = Wt3 + (size_t)(ct * 16 + (lane & 15)) * DIM + kg * 8;
#pragma unroll
        for (int k0 = 0; k0 < 4; ++k0) {
            f16x8 b = *(const f16x8*)(Bbase + k0 * 32);
            acc2[ct] = __builtin_amdgcn_mfma_f32_16x16x32_f16(a2[k0], b, acc2[ct], 0, 0, 0);
        }
    }

    int rbase = row0 + (lane >> 4) * 4;
#pragma unroll
    for (int r = 0; r < 4; ++r) {
        int row = rbase + r;
        if (row >= n) continue;
#pragma unroll
        for (int ct = 0; ct < 3; ++ct) {
            int cc = ct * 16 + col;
            if (cc < 40)
                g3h[(size_t)row * 40 + cc] = __float2half(acc2[ct][r]);
        }
    }
}

// Final agg over fp16 [N][40] rows -> fp32 d_out. 16-lane group per node.
__global__ __launch_bounds__(256) void agg40_kernel(
        const __half* __restrict__ hin, const float* __restrict__ nrm,
        const int* __restrict__ off, const int* __restrict__ csr,
        float* __restrict__ out, int N) {
    int t = threadIdx.x;
    int lane = t & 63, wv = t >> 6;
    int g = lane >> 4, pos = lane & 15;
    int node = blockIdx.x * 16 + wv * 4 + g;
    if (node >= N || pos >= 10) return;
    int b = off[node], e = off[node + 1];
    float4 a0 = make_float4(0,0,0,0), a1 = a0, a2 = a0, a3 = a0;
    int j = b;
    for (; j + 3 < e; j += 4) {
        int s0 = csr[j], s1 = csr[j+1], s2 = csr[j+2], s3 = csr[j+3];
        uint2 u0 = *(const uint2*)&hin[(size_t)s0 * 40 + pos * 4];
        uint2 u1 = *(const uint2*)&hin[(size_t)s1 * 40 + pos * 4];
        uint2 u2 = *(const uint2*)&hin[(size_t)s2 * 40 + pos * 4];
        uint2 u3 = *(const uint2*)&hin[(size_t)s3 * 40 + pos * 4];
        float2 f;
        f = __half22float2(*(__half2*)&u0.x); a0.x+=f.x; a0.y+=f.y;
        f = __half22float2(*(__half2*)&u0.y); a0.z+=f.x; a0.w+=f.y;
        f = __half22float2(*(__half2*)&u1.x); a1.x+=f.x; a1.y+=f.y;
        f = __half22float2(*(__half2*)&u1.y); a1.z+=f.x; a1.w+=f.y;
        f = __half22float2(*(__half2*)&u2.x); a2.x+=f.x; a2.y+=f.y;
        f = __half22float2(*(__half2*)&u2.y); a2.z+=f.x; a2.w+=f.y;
        f = __half22float2(*(__half2*)&u3.x); a3.x+=f.x; a3.y+=f.y;
        f = __half22float2(*(__half2*)&u3.y); a3.z+=f.x; a3.w+=f.y;
    }
    for (; j < e; ++j) {
        uint2 u = *(const uint2*)&hin[(size_t)csr[j] * 40 + pos * 4];
        float2 f;
        f = __half22float2(*(__half2*)&u.x); a0.x+=f.x; a0.y+=f.y;
        f = __half22float2(*(__half2*)&u.y); a0.z+=f.x; a0.w+=f.y;
    }
    float s = nrm[node];
    float4 r;
    r.x = ((a0.x+a1.x) + (a2.x+a3.x)) * s;
    r.y = ((a0.y+a1.y) + (a2.y+a3.y)) * s;
    r.z = ((a0.z+a1.z) + (a2.z+a3.z)) * s;
    r.w = ((a0.w+a1.w) + (a2.w+a3.w)) * s;
    *(float4*)&out[(size_t)node * 40 + pos * 4] = r;
}

extern "C" void kernel_launch(void* const* d_in, const int* in_sizes, int n_in,
                              void* d_out, int out_size, void* d_ws, size_t ws_size,
                              hipStream_t stream) {
    const float* features = (const float*)d_in[0];
    const int*   edges    = (const int*)d_in[1];
    const float* W0       = (const float*)d_in[2];
    const float* W1       = (const float*)d_in[3];
    const float* W2       = (const float*)d_in[4];
    const float* W3       = (const float*)d_in[5];

    const int N = in_sizes[0] / DIM;       // 50000
    const int E = in_sizes[1] / 2;         // 640000
    const int* src = edges;
    const int* dst = edges + E;

    char* p = (char*)d_ws;
    __half* featH = (__half*)p; p += (size_t)N * DIM * 2;
    __half* agg16 = (__half*)p; p += (size_t)N * DIM * 2;
    __half* h16   = (__half*)p; p += (size_t)N * DIM * 2;
    __half* g3h   = (__half*)p; p += (size_t)N * 64 * 2;
    __half* Wt    = (__half*)p; p += (size_t)(3 * 128 * 128 + 48 * 128) * 2;
    float*  nrm   = (float*)p;  p += (size_t)N * 4;
    int*    deg   = (int*)p;    p += (size_t)N * 4;
    int*    cur   = (int*)p;    p += (size_t)N * 4;
    int*    off   = (int*)p;    p += (size_t)(N + 1) * 4;
    int*    bsum  = (int*)p;    p += 64 * 4;
    int*    csr   = (int*)p;    p += (size_t)E * 4;
    (void)ws_size; (void)n_in; (void)out_size;

    hipMemsetAsync(deg, 0, (size_t)N * sizeof(int), stream);

    int eb = (E + 255) / 256;
    int G  = (N + CHUNK - 1) / CHUNK;      // 49
    deg_kernel   <<<eb, 256, 0, stream>>>(dst, deg, E);
    scanA_kernel <<<G, 256, 0, stream>>>(deg, nrm, bsum, N);
    scanBC_kernel<<<G, 256, 0, stream>>>(deg, bsum, off, cur, N, G);
    fill_kernel  <<<eb, 256, 0, stream>>>(src, dst, off, cur, csr, E);

    int n4 = N * (DIM / 4);
    int prepTot = n4 + 3 * 128 * 128 + 48 * 128;
    prep_kernel<<<(prepTot + 255) / 256, 256, 0, stream>>>(
        features, nrm, W0, W1, W2, W3, featH, Wt, n4);

    int gb = (N + 63) / 64;
    int ab = (N + 3) / 4;
    aggh_kernel<<<ab, 256, 0, stream>>>(featH, nrm, off, csr, agg16, N);
    gemmM_kernel<<<gb, 256, 0, stream>>>(agg16, Wt, nrm, h16, N);

    aggh_kernel<<<ab, 256, 0, stream>>>(h16, nrm, off, csr, agg16, N);
    gemmM_kernel<<<gb, 256, 0, stream>>>(agg16, Wt + 128 * 128, nrm, h16, N);

    aggh_kernel<<<ab, 256, 0, stream>>>(h16, nrm, off, csr, agg16, N);
    gemmM2_kernel<<<gb, 256, 0, stream>>>(agg16, Wt + 2 * 128 * 128,
                                          Wt + 3 * 128 * 128, nrm, g3h, N);

    agg40_kernel<<<(N + 15) / 16, 256, 0, stream>>>(g3h, nrm, off, csr,
                                                    (float*)d_out, N);
}

// Round 15
// 248.988 us; speedup vs baseline: 2.9848x; 1.0131x over previous
//
#include <hip/hip_runtime.h>
#include <hip/hip_fp16.h>

// GCN: 4 layers, N=50000, E=640000, d=128 (last 128->40).
// R15: consolidation. prep merged into scanBC (wide grid: 49 scan blocks +
// all blocks convert featH/Wt). g3h padded to [N][64] fp16 = one aligned
// 128B line per row for the final gather. 11 dispatches.
// aggh (L3 random-gather wall, ~34us) is the control.

#define DIM 128
#define CHUNK 1024
#define HS_LD 136          // padded LDS row stride (halves)

typedef __attribute__((ext_vector_type(8))) _Float16 f16x8;
typedef __attribute__((ext_vector_type(4))) float f32x4;

__global__ void deg_kernel(const int* __restrict__ dst, int* __restrict__ deg, int E) {
    int i = blockIdx.x * blockDim.x + threadIdx.x;
    if (i < E) atomicAdd(&deg[dst[i]], 1);
}

// Phase A: per-chunk sums of deg; also computes nrm = rsqrt(max(deg,1)).
__global__ __launch_bounds__(256) void scanA_kernel(
        const int* __restrict__ deg, float* __restrict__ nrm,
        int* __restrict__ bsum, int n) {
    int b = blockIdx.x, t = threadIdx.x;
    int base = b * CHUNK + t * 4;
    int s = 0;
    if (base + 3 < n) {
        int4 d = *(const int4*)&deg[base];
        s = d.x + d.y + d.z + d.w;
        float4 r;
        r.x = rsqrtf(fmaxf((float)d.x, 1.0f));
        r.y = rsqrtf(fmaxf((float)d.y, 1.0f));
        r.z = rsqrtf(fmaxf((float)d.z, 1.0f));
        r.w = rsqrtf(fmaxf((float)d.w, 1.0f));
        *(float4*)&nrm[base] = r;
    } else {
        for (int j = 0; j < 4; ++j) {
            int idx = base + j;
            if (idx < n) {
                int d = deg[idx];
                s += d;
                nrm[idx] = rsqrtf(fmaxf((float)d, 1.0f));
            }
        }
    }
    for (int o = 32; o; o >>= 1) s += __shfl_down(s, o, 64);
    __shared__ int ws[4];
    if ((t & 63) == 0) ws[t >> 6] = s;
    __syncthreads();
    if (t == 0) bsum[b] = ws[0] + ws[1] + ws[2] + ws[3];
}

// Merged B+C+prep: blocks < G do {bsum scan, cur zero, off write}; ALL
// blocks grid-stride featH = features*nrm (fp16) and Wt (fp16 transposed W).
__global__ __launch_bounds__(256) void scanBCprep_kernel(
        const int* __restrict__ deg, const int* __restrict__ bsum,
        int* __restrict__ off, int* __restrict__ cur,
        const float* __restrict__ f, const float* __restrict__ nrm,
        const float* __restrict__ W0, const float* __restrict__ W1,
        const float* __restrict__ W2, const float* __restrict__ W3,
        __half* __restrict__ featH, __half* __restrict__ Wt,
        int n, int G) {
    __shared__ int pbs;
    __shared__ int wsum[4];
    int b = blockIdx.x, t = threadIdx.x;
    if (b < G) {
        if (t < 64) {
            int orig = (t < G) ? bsum[t] : 0;
            int v = orig;
            for (int o = 1; o < 64; o <<= 1) {
                int u = __shfl_up(v, o, 64);
                if (t >= o) v += u;
            }
            if (b == 0 && t == G - 1) off[n] = v;   // grand total
            if (t == b) pbs = v - orig;             // exclusive prefix of chunk b
        }
        int base = b * CHUNK + t * 4;
        if (base + 3 < n) *(int4*)&cur[base] = make_int4(0, 0, 0, 0);
        else for (int j = 0; j < 4; ++j) if (base + j < n) cur[base + j] = 0;

        int d0 = 0, d1 = 0, d2 = 0, d3 = 0;
        if (base + 3 < n) {
            int4 d = *(const int4*)&deg[base];
            d0 = d.x; d1 = d.y; d2 = d.z; d3 = d.w;
        } else {
            if (base     < n) d0 = deg[base];
            if (base + 1 < n) d1 = deg[base + 1];
            if (base + 2 < n) d2 = deg[base + 2];
        }
        int tot = d0 + d1 + d2 + d3;
        int v = tot;
        for (int o = 1; o < 64; o <<= 1) {
            int u = __shfl_up(v, o, 64);
            if ((t & 63) >= o) v += u;
        }
        if ((t & 63) == 63) wsum[t >> 6] = v;
        __syncthreads();
        int wbase = 0;
        for (int w = 0; w < (t >> 6); ++w) wbase += wsum[w];
        int p = pbs + wbase + (v - tot);
        if (base + 3 < n) {
            int4 o4 = make_int4(p, p + d0, p + d0 + d1, p + d0 + d1 + d2);
            *(int4*)&off[base] = o4;
        } else {
            if (base     < n) off[base]     = p;
            if (base + 1 < n) off[base + 1] = p + d0;
            if (base + 2 < n) off[base + 2] = p + d0 + d1;
        }
    }

    // prep (all blocks, grid-stride): featH + Wt
    int gtid = b * 256 + t;
    int gsz = gridDim.x * 256;
    int n4 = n * 32;
    for (int i = gtid; i < n4; i += gsz) {
        int r = i >> 5, c4 = i & 31;
        float s = nrm[r];
        float4 v = ((const float4*)f)[i];
        __half2 lo = __float22half2_rn(make_float2(v.x * s, v.y * s));
        __half2 hi = __float22half2_rn(make_float2(v.z * s, v.w * s));
        uint2 u;
        u.x = *(unsigned int*)&lo;
        u.y = *(unsigned int*)&hi;
        *(uint2*)&featH[(size_t)r * DIM + c4 * 4] = u;
    }
    const int WTOT = 3 * 128 * 128 + 48 * 128;
    for (int w = gtid; w < WTOT; w += gsz) {
        if (w < 3 * 128 * 128) {
            int l = w >> 14, c = (w >> 7) & 127, k = w & 127;
            const float* W = (l == 0) ? W0 : ((l == 1) ? W1 : W2);
            Wt[w] = __float2half(W[k * 128 + c]);
        } else {
            int j = w - 3 * 128 * 128;
            int c = j >> 7, k = j & 127;
            Wt[w] = __float2half((c < 40) ? W3[k * 40 + c] : 0.f);
        }
    }
}

__global__ void fill_kernel(const int* __restrict__ src, const int* __restrict__ dst,
                            const int* __restrict__ off, int* __restrict__ cur,
                            int* __restrict__ csr, int E) {
    int i = blockIdx.x * blockDim.x + threadIdx.x;
    if (i < E) {
        int d = dst[i];
        int p = atomicAdd(&cur[d], 1);
        csr[off[d] + p] = src[i];
    }
}

// fp16 gather (the control — at the L3 random-gather wall).
__global__ __launch_bounds__(256) void aggh_kernel(
        const __half* __restrict__ hin, const float* __restrict__ nrm,
        const int* __restrict__ off, const int* __restrict__ csr,
        __half* __restrict__ out, int N) {
    int t = threadIdx.x;
    int lane = t & 63;
    int node = blockIdx.x * 4 + (t >> 6);
    if (node >= N) return;
    int pos = lane & 15, sg = lane >> 4;
    int c = pos * 8;
    int b = off[node], e = off[node + 1];
    float a[8] = {0,0,0,0,0,0,0,0};
    float bb[8] = {0,0,0,0,0,0,0,0};
    int j = b + sg;
    for (; j + 4 < e; j += 8) {
        int s0 = csr[j], s1 = csr[j + 4];
        uint4 u0 = *(const uint4*)&hin[(size_t)s0 * DIM + c];
        uint4 u1 = *(const uint4*)&hin[(size_t)s1 * DIM + c];
        float2 f;
        f = __half22float2(*(__half2*)&u0.x); a[0]+=f.x; a[1]+=f.y;
        f = __half22float2(*(__half2*)&u0.y); a[2]+=f.x; a[3]+=f.y;
        f = __half22float2(*(__half2*)&u0.z); a[4]+=f.x; a[5]+=f.y;
        f = __half22float2(*(__half2*)&u0.w); a[6]+=f.x; a[7]+=f.y;
        f = __half22float2(*(__half2*)&u1.x); bb[0]+=f.x; bb[1]+=f.y;
        f = __half22float2(*(__half2*)&u1.y); bb[2]+=f.x; bb[3]+=f.y;
        f = __half22float2(*(__half2*)&u1.z); bb[4]+=f.x; bb[5]+=f.y;
        f = __half22float2(*(__half2*)&u1.w); bb[6]+=f.x; bb[7]+=f.y;
    }
    for (; j < e; j += 4) {
        uint4 u = *(const uint4*)&hin[(size_t)csr[j] * DIM + c];
        float2 f;
        f = __half22float2(*(__half2*)&u.x); a[0]+=f.x; a[1]+=f.y;
        f = __half22float2(*(__half2*)&u.y); a[2]+=f.x; a[3]+=f.y;
        f = __half22float2(*(__half2*)&u.z); a[4]+=f.x; a[5]+=f.y;
        f = __half22float2(*(__half2*)&u.w); a[6]+=f.x; a[7]+=f.y;
    }
#pragma unroll
    for (int k = 0; k < 8; ++k) a[k] += bb[k];
#pragma unroll
    for (int k = 0; k < 8; ++k) {
        a[k] += __shfl_xor(a[k], 16, 64);
        a[k] += __shfl_xor(a[k], 32, 64);
    }
    if (sg == 0) {
        float s = nrm[node];
        __half2 h0 = __float22half2_rn(make_float2(a[0]*s, a[1]*s));
        __half2 h1 = __float22half2_rn(make_float2(a[2]*s, a[3]*s));
        __half2 h2 = __float22half2_rn(make_float2(a[4]*s, a[5]*s));
        __half2 h3 = __float22half2_rn(make_float2(a[6]*s, a[7]*s));
        uint4 u;
        u.x = *(unsigned int*)&h0; u.y = *(unsigned int*)&h1;
        u.z = *(unsigned int*)&h2; u.w = *(unsigned int*)&h3;
        *(uint4*)&out[(size_t)node * DIM + c] = u;
    }
}

// MFMA GEMM (layers 0,1): C[64x128] = A @ Wt, relu+nrm, fp16 out.
__global__ __launch_bounds__(256) void gemmM_kernel(
        const __half* __restrict__ Ah, const __half* __restrict__ Wt,
        const float* __restrict__ nrm, __half* __restrict__ outh, int n) {
    int t = threadIdx.x;
    int lane = t & 63, wv = t >> 6;
    int row0 = blockIdx.x * 64 + wv * 16;
    int arow = row0 + (lane & 15);
    int ar = (arow < n) ? arow : (n - 1);
    int kg = lane >> 4;

    const __half* Abase = Ah + (size_t)ar * DIM + kg * 8;
    f16x8 a[4];
#pragma unroll
    for (int k0 = 0; k0 < 4; ++k0)
        a[k0] = *(const f16x8*)(Abase + k0 * 32);

    f32x4 acc[8];
#pragma unroll
    for (int ct = 0; ct < 8; ++ct) {
        acc[ct] = (f32x4){0.f, 0.f, 0.f, 0.f};
        const __half* Bbase = Wt + (size_t)(ct * 16 + (lane & 15)) * DIM + kg * 8;
#pragma unroll
        for (int k0 = 0; k0 < 4; ++k0) {
            f16x8 b = *(const f16x8*)(Bbase + k0 * 32);
            acc[ct] = __builtin_amdgcn_mfma_f32_16x16x32_f16(a[k0], b, acc[ct], 0, 0, 0);
        }
    }

    int col = lane & 15;
    int rbase = row0 + (lane >> 4) * 4;
#pragma unroll
    for (int r = 0; r < 4; ++r) {
        int row = rbase + r;
        if (row >= n) continue;
        float s = nrm[row];
#pragma unroll
        for (int ct = 0; ct < 8; ++ct) {
            float v = fmaxf(acc[ct][r], 0.f) * s;
            outh[(size_t)row * DIM + ct * 16 + col] = __float2half(v);
        }
    }
}

// Fused layer-2 GEMM + layer-3 GEMM (h2 tile stays in LDS).
// g3h is [n][64] fp16 (cols 48-63 zeroed) — one aligned 128B line per row.
__global__ __launch_bounds__(256) void gemmM2_kernel(
        const __half* __restrict__ Ah, const __half* __restrict__ Wt2,
        const __half* __restrict__ Wt3, const float* __restrict__ nrm,
        __half* __restrict__ g3h, int n) {
    __shared__ __half Hs[64 * HS_LD];
    int t = threadIdx.x;
    int lane = t & 63, wv = t >> 6;
    int row0 = blockIdx.x * 64 + wv * 16;
    int arow = row0 + (lane & 15);
    int ar = (arow < n) ? arow : (n - 1);
    int kg = lane >> 4;

    const __half* Abase = Ah + (size_t)ar * DIM + kg * 8;
    f16x8 a[4];
#pragma unroll
    for (int k0 = 0; k0 < 4; ++k0)
        a[k0] = *(const f16x8*)(Abase + k0 * 32);

    f32x4 acc[8];
#pragma unroll
    for (int ct = 0; ct < 8; ++ct) {
        acc[ct] = (f32x4){0.f, 0.f, 0.f, 0.f};
        const __half* Bbase = Wt2 + (size_t)(ct * 16 + (lane & 15)) * DIM + kg * 8;
#pragma unroll
        for (int k0 = 0; k0 < 4; ++k0) {
            f16x8 b = *(const f16x8*)(Bbase + k0 * 32);
            acc[ct] = __builtin_amdgcn_mfma_f32_16x16x32_f16(a[k0], b, acc[ct], 0, 0, 0);
        }
    }

    int col = lane & 15;
    int lr0 = wv * 16 + (lane >> 4) * 4;
#pragma unroll
    for (int r = 0; r < 4; ++r) {
        int lrow = lr0 + r;
        int grow = blockIdx.x * 64 + lrow;
        float s = (grow < n) ? nrm[grow] : 0.f;
#pragma unroll
        for (int ct = 0; ct < 8; ++ct) {
            float v = fmaxf(acc[ct][r], 0.f) * s;
            Hs[lrow * HS_LD + ct * 16 + col] = __float2half(v);
        }
    }
    __syncthreads();

    // part 2: [64x48] = Hs @ Wt3 (3 col-tiles), store [n][64] fp16 (pad 0)
    int lrowA = wv * 16 + (lane & 15);
    const __half* Hbase = &Hs[lrowA * HS_LD + kg * 8];
    f16x8 a2[4];
#pragma unroll
    for (int k0 = 0; k0 < 4; ++k0)
        a2[k0] = *(const f16x8*)(Hbase + k0 * 32);

    f32x4 acc2[3];
#pragma unroll
    for (int ct = 0; ct < 3; ++ct) {
        acc2[ct] = (f32x4){0.f, 0.f, 0.f, 0.f};
        const __half* Bbase = Wt3 + (size_t)(ct * 16 + (lane & 15)) * DIM + kg * 8;
#pragma unroll
        for (int k0 = 0; k0 < 4; ++k0) {
            f16x8 b = *(const f16x8*)(Bbase + k0 * 32);
            acc2[ct] = __builtin_amdgcn_mfma_f32_16x16x32_f16(a2[k0], b, acc2[ct], 0, 0, 0);
        }
    }

    int rbase = row0 + (lane >> 4) * 4;
#pragma unroll
    for (int r = 0; r < 4; ++r) {
        int row = rbase + r;
        if (row >= n) continue;
#pragma unroll
        for (int ct = 0; ct < 3; ++ct)
            g3h[(size_t)row * 64 + ct * 16 + col] = __float2half(acc2[ct][r]);
        g3h[(size_t)row * 64 + 48 + col] = __float2half(0.f);  // pad
    }
}

// Final agg over fp16 [N][64] rows (one aligned line each) -> fp32 d_out
// [N][40]. 16-lane group gathers the full line; pos<10 write.
__global__ __launch_bounds__(256) void agg40_kernel(
        const __half* __restrict__ hin, const float* __restrict__ nrm,
        const int* __restrict__ off, const int* __restrict__ csr,
        float* __restrict__ out, int N) {
    int t = threadIdx.x;
    int lane = t & 63, wv = t >> 6;
    int g = lane >> 4, pos = lane & 15;
    int node = blockIdx.x * 16 + wv * 4 + g;
    if (node >= N) return;
    int b = off[node], e = off[node + 1];
    float4 a0 = make_float4(0,0,0,0), a1 = a0, a2 = a0, a3 = a0;
    int j = b;
    for (; j + 3 < e; j += 4) {
        int s0 = csr[j], s1 = csr[j+1], s2 = csr[j+2], s3 = csr[j+3];
        uint2 u0 = *(const uint2*)&hin[(size_t)s0 * 64 + pos * 4];
        uint2 u1 = *(const uint2*)&hin[(size_t)s1 * 64 + pos * 4];
        uint2 u2 = *(const uint2*)&hin[(size_t)s2 * 64 + pos * 4];
        uint2 u3 = *(const uint2*)&hin[(size_t)s3 * 64 + pos * 4];
        float2 f;
        f = __half22float2(*(__half2*)&u0.x); a0.x+=f.x; a0.y+=f.y;
        f = __half22float2(*(__half2*)&u0.y); a0.z+=f.x; a0.w+=f.y;
        f = __half22float2(*(__half2*)&u1.x); a1.x+=f.x; a1.y+=f.y;
        f = __half22float2(*(__half2*)&u1.y); a1.z+=f.x; a1.w+=f.y;
        f = __half22float2(*(__half2*)&u2.x); a2.x+=f.x; a2.y+=f.y;
        f = __half22float2(*(__half2*)&u2.y); a2.z+=f.x; a2.w+=f.y;
        f = __half22float2(*(__half2*)&u3.x); a3.x+=f.x; a3.y+=f.y;
        f = __half22float2(*(__half2*)&u3.y); a3.z+=f.x; a3.w+=f.y;
    }
    for (; j < e; ++j) {
        uint2 u = *(const uint2*)&hin[(size_t)csr[j] * 64 + pos * 4];
        float2 f;
        f = __half22float2(*(__half2*)&u.x); a0.x+=f.x; a0.y+=f.y;
        f = __half22float2(*(__half2*)&u.y); a0.z+=f.x; a0.w+=f.y;
    }
    if (pos >= 10) return;                 // cols 40+ are padding
    float s = nrm[node];
    float4 r;
    r.x = ((a0.x+a1.x) + (a2.x+a3.x)) * s;
    r.y = ((a0.y+a1.y) + (a2.y+a3.y)) * s;
    r.z = ((a0.z+a1.z) + (a2.z+a3.z)) * s;
    r.w = ((a0.w+a1.w) + (a2.w+a3.w)) * s;
    *(float4*)&out[(size_t)node * 40 + pos * 4] = r;
}

extern "C" void kernel_launch(void* const* d_in, const int* in_sizes, int n_in,
                              void* d_out, int out_size, void* d_ws, size_t ws_size,
                              hipStream_t stream) {
    const float* features = (const float*)d_in[0];
    const int*   edges    = (const int*)d_in[1];
    const float* W0       = (const float*)d_in[2];
    const float* W1       = (const float*)d_in[3];
    const float* W2       = (const float*)d_in[4];
    const float* W3       = (const float*)d_in[5];

    const int N = in_sizes[0] / DIM;       // 50000
    const int E = in_sizes[1] / 2;         // 640000
    const int* src = edges;
    const int* dst = edges + E;

    char* p = (char*)d_ws;
    __half* featH = (__half*)p; p += (size_t)N * DIM * 2;
    __half* agg16 = (__half*)p; p += (size_t)N * DIM * 2;
    __half* h16   = (__half*)p; p += (size_t)N * DIM * 2;
    __half* g3h   = (__half*)p; p += (size_t)N * 64 * 2;
    __half* Wt    = (__half*)p; p += (size_t)(3 * 128 * 128 + 48 * 128) * 2;
    float*  nrm   = (float*)p;  p += (size_t)N * 4;
    int*    deg   = (int*)p;    p += (size_t)N * 4;
    int*    cur   = (int*)p;    p += (size_t)N * 4;
    int*    off   = (int*)p;    p += (size_t)(N + 1) * 4;
    int*    bsum  = (int*)p;    p += 64 * 4;
    int*    csr   = (int*)p;    p += (size_t)E * 4;
    (void)ws_size; (void)n_in; (void)out_size;

    hipMemsetAsync(deg, 0, (size_t)N * sizeof(int), stream);

    int eb = (E + 255) / 256;
    int G  = (N + CHUNK - 1) / CHUNK;      // 49
    deg_kernel  <<<eb, 256, 0, stream>>>(dst, deg, E);
    scanA_kernel<<<G, 256, 0, stream>>>(deg, nrm, bsum, N);
    scanBCprep_kernel<<<392, 256, 0, stream>>>(deg, bsum, off, cur,
                                               features, nrm, W0, W1, W2, W3,
                                               featH, Wt, N, G);
    fill_kernel <<<eb, 256, 0, stream>>>(src, dst, off, cur, csr, E);

    int gb = (N + 63) / 64;
    int ab = (N + 3) / 4;
    aggh_kernel<<<ab, 256, 0, stream>>>(featH, nrm, off, csr, agg16, N);
    gemmM_kernel<<<gb, 256, 0, stream>>>(agg16, Wt, nrm, h16, N);

    aggh_kernel<<<ab, 256, 0, stream>>>(h16, nrm, off, csr, agg16, N);
    gemmM_kernel<<<gb, 256, 0, stream>>>(agg16, Wt + 128 * 128, nrm, h16, N);

    aggh_kernel<<<ab, 256, 0, stream>>>(h16, nrm, off, csr, agg16, N);
    gemmM2_kernel<<<gb, 256, 0, stream>>>(agg16, Wt + 2 * 128 * 128,
                                          Wt + 3 * 128 * 128, nrm, g3h, N);

    agg40_kernel<<<(N + 15) / 16, 256, 0, stream>>>(g3h, nrm, off, csr,
                                                    (float*)d_out, N);
}